// Round 6
// baseline (217.217 us; speedup 1.0000x reference)
//
#include <hip/hip_runtime.h>
#include <cstddef>

#define NB 4
#define NC 256
#define ND 128
#define NH 128
#define NW 128
#define NHW (NH*NW)
#define NT 16384
#define NBKT 1024   // 4 batches x 16x16 tiles of 8x8 px

typedef short   short8  __attribute__((ext_vector_type(8)));
typedef unsigned short ushort8 __attribute__((ext_vector_type(8)));
typedef float   floatx4 __attribute__((ext_vector_type(4)));
typedef float   floatx2 __attribute__((ext_vector_type(2)));

// RNE fp32->bf16 pack of two floats into one dword (low ushort = first arg)
__device__ __forceinline__ unsigned pk_bf16(float a, float b) {
    unsigned ua = __float_as_uint(a);
    unsigned ub = __float_as_uint(b);
    ua += 0x7fffu + ((ua >> 16) & 1u);
    ub += 0x7fffu + ((ub >> 16) & 1u);
    return (ua >> 16) | (ub & 0xffff0000u);
}

__device__ __forceinline__ float bf2f(unsigned short u) {
    return __uint_as_float(((unsigned)u) << 16);
}

// ---- fp8 e4m3 (OCP) helpers: HW cvt on gfx950 ----
__device__ __forceinline__ unsigned fp8x4_from_f32(float v0, float v1, float v2, float v3) {
    int r = 0;
    r = __builtin_amdgcn_cvt_pk_fp8_f32(v0, v1, r, false);
    r = __builtin_amdgcn_cvt_pk_fp8_f32(v2, v3, r, true);
    return (unsigned)r;
}
template <bool HI>
__device__ __forceinline__ floatx2 fp8x2_to_f32(unsigned w) {
    return __builtin_amdgcn_cvt_pk_f32_fp8((int)w, HI);
}

// bucket id for a point: (batch, ytile, xtile); MUST be identical in hist & scatter
__device__ __forceinline__ int bucket_of(float cx, float cy, int b) {
    int x0 = (int)floorf(cx * (float)(NW - 1));
    int y0 = (int)floorf(cy * (float)(NH - 1));
    x0 = min(max(x0, 0), NW - 1);
    y0 = min(max(y0, 0), NH - 1);
    return b * 256 + (y0 >> 3) * 16 + (x0 >> 3);
}

// ---- prep: zero counts+cursor, build W1T (W1T[d][e] = W1[e][d]) ----
__global__ void prep_kernel(const float* __restrict__ W1, float* __restrict__ W1T,
                            int* __restrict__ counts, int* __restrict__ cursor)
{
    const int t = threadIdx.x;   // 1024 threads, 1 block
    counts[t] = 0;
    cursor[t] = 0;
    for (int i = t; i < ND*ND; i += 1024)
        W1T[(i & 127)*ND + (i >> 7)] = W1[i];
}

// ---- hist: count points per bucket ----
__global__ __launch_bounds__(1024)
void hist_kernel(const float* __restrict__ coords, int* __restrict__ counts)
{
    const int g = blockIdx.x * 1024 + threadIdx.x;   // [0, 65536)
    const float cx = coords[(size_t)g*2 + 0];
    const float cy = coords[(size_t)g*2 + 1];
    atomicAdd(&counts[bucket_of(cx, cy, g >> 14)], 1);
}

// ---- scan: exclusive prefix over 1024 bucket counts ----
__global__ __launch_bounds__(1024)
void scan_kernel(const int* __restrict__ counts, int* __restrict__ starts)
{
    __shared__ int sd[1024];
    const int t = threadIdx.x;
    const int my = counts[t];
    sd[t] = my;
    __syncthreads();
    for (int off = 1; off < 1024; off <<= 1) {
        int v = (t >= off) ? sd[t - off] : 0;
        __syncthreads();
        sd[t] += v;
        __syncthreads();
    }
    starts[t] = sd[t] - my;   // exclusive
}

// ---- scatter: order[] = point ids grouped by bucket ----
__global__ __launch_bounds__(1024)
void scatter_kernel(const float* __restrict__ coords, const int* __restrict__ starts,
                    int* __restrict__ cursor, int* __restrict__ order)
{
    const int g = blockIdx.x * 1024 + threadIdx.x;
    const float cx = coords[(size_t)g*2 + 0];
    const float cy = coords[(size_t)g*2 + 1];
    const int bkt = bucket_of(cx, cy, g >> 14);
    const int pos = atomicAdd(&cursor[bkt], 1);
    order[starts[bkt] + pos] = g;
}

// Kernel: vm[b][p][d] = sum_c fmap[b][c][p] * Wp[d][c], OUTPUT fp8 e4m3 channel-last.
// Wp staged once per block into LDS as bf16 A-fragments (64 KB). K-loop FULLY
// unrolled: up to 64 independent strided B-dwords in flight per wave (round-5
// was ~8 -> latency-bound at 45us). 512 thr, 128 px/block, grid 512.
__global__ __launch_bounds__(512, 4)
void proj_kernel(const float* __restrict__ fmap, const float* __restrict__ Wp,
                 unsigned char* __restrict__ vm)
{
    const int bi = blockIdx.x;
    __shared__ unsigned short awp[8*8*64*8];   // [dt][ch][lane][8 bf16] = 64 KB

    const int t    = threadIdx.x;
    const int lane = t & 63;
    const int w    = t >> 6;       // wave id 0..7
    const int l15  = lane & 15;
    const int q    = lane >> 4;
    const int cq   = q * 8;

    // ---- stage Wp -> LDS A-fragments ----
    {
        const int dt = w;
        const float* wr0 = Wp + (size_t)(dt*16 + l15)*NC + cq;
        #pragma unroll
        for (int ch = 0; ch < 8; ++ch) {
            float4 g0 = *(const float4*)(wr0 + ch*32);
            float4 g1 = *(const float4*)(wr0 + ch*32 + 4);
            uint4 pk = make_uint4(pk_bf16(g0.x,g0.y), pk_bf16(g0.z,g0.w),
                                  pk_bf16(g1.x,g1.y), pk_bf16(g1.z,g1.w));
            *(uint4*)&awp[((dt*8 + ch)*64 + lane)*8] = pk;
        }
    }
    __syncthreads();

    const int b    = (bi & 7) >> 1;                 // XCD-aware: 2 XCDs per batch
    const int slot = ((bi >> 3) << 1) | (bi & 1);   // [0,128)
    const int p    = slot*128 + w*16 + l15;

    floatx4 acc[8];
    #pragma unroll
    for (int i = 0; i < 8; ++i) acc[i] = (floatx4)(0.f);

    const float* fbase = fmap + (size_t)b*NC*NHW + p;

    #pragma unroll
    for (int c0 = 0; c0 < 8; ++c0) {
        const float* bp = fbase + (size_t)(c0*32 + cq)*NHW;
        float f[8];
        #pragma unroll
        for (int j = 0; j < 8; ++j) f[j] = bp[(size_t)j*NHW];
        union { short8 v; unsigned u[4]; } bc;
        #pragma unroll
        for (int j = 0; j < 4; ++j) bc.u[j] = pk_bf16(f[2*j], f[2*j+1]);
        #pragma unroll
        for (int dt = 0; dt < 8; ++dt) {
            short8 afr = *(const short8*)&awp[((dt*8 + c0)*64 + lane)*8];
            acc[dt] = __builtin_amdgcn_mfma_f32_16x16x32_bf16(afr, bc.v, acc[dt], 0, 0, 0);
        }
    }
    // ---- epilogue: C row=(q*4+reg)->d, col=l15->p; pack 4 d to fp8 dword ----
    unsigned char* vrow = vm + ((size_t)(b*NHW + p))*ND;
    #pragma unroll
    for (int dt = 0; dt < 8; ++dt) {
        floatx4 v = acc[dt];
        *(unsigned*)&vrow[dt*16 + q*4] = fp8x4_from_f32(v[0], v[1], v[2], v[3]);
    }
}

// Gather+MLP over SPATIALLY SORTED points: block = bucket (8x8-px tile of one
// batch). vm working set per block = 11x11 px x 128 B = 15.5 KB -> L1-resident
// after first touch. Points processed in chunks of 64 (avg bucket = 64).
__global__ __launch_bounds__(512, 4)
void gather_mlp(const unsigned char* __restrict__ vm, const float* __restrict__ coords,
                const int* __restrict__ counts, const int* __restrict__ starts,
                const int* __restrict__ order,
                const float* __restrict__ W1T, const float* __restrict__ b1,
                const float* __restrict__ W2, const float* __restrict__ b2,
                float* __restrict__ out)
{
    __shared__ unsigned short feat[64 * 136];
    __shared__ float part[64][17];
    __shared__ int gidx[64];
    const int t   = threadIdx.x;
    const int bkt = blockIdx.x;
    const int n     = counts[bkt];
    const int start = starts[bkt];
    const int chunks = (n + 63) >> 6;

    for (int c = 0; c < chunks; ++c) {
        const int np = min(n - c*64, 64);

        // ---- Phase A: gather. 8 threads per point, 16 fp8 channels each. ----
        {
            const int pt = t >> 3;
            const int c8 = t & 7;
            if (pt < np) {
                const int g = order[start + c*64 + pt];
                if (c8 == 0) gidx[pt] = g;
                const int b = g >> 14;
                const float cx = coords[(size_t)g*2 + 0];
                const float cy = coords[(size_t)g*2 + 1];
                const float ix = cx * (float)(NW - 1);
                const float iy = cy * (float)(NH - 1);
                const float x0f = floorf(ix), y0f = floorf(iy);
                const int x0 = (int)x0f, y0 = (int)y0f;
                const float wx1 = ix - x0f, wy1 = iy - y0f;
                const float wxv[4] = {1.f - wx1, 1.f, 1.f, wx1};
                const float wyv[4] = {1.f - wy1, 1.f, 1.f, wy1};
                floatx2 acc[8];
                #pragma unroll
                for (int k = 0; k < 8; ++k) acc[k] = (floatx2)(0.f);
                const unsigned char* vmb = vm + (size_t)b*NHW*ND + c8*16;
                #pragma unroll
                for (int j = 0; j < 4; ++j) {
                    const int Y  = y0 - 1 + j;
                    const int Yc = min(max(Y, 0), NH-1);
                    const bool vy = (Y >= 0) & (Y < NH);
                    #pragma unroll
                    for (int i = 0; i < 4; ++i) {
                        const int X  = x0 - 1 + i;
                        const int Xc = min(max(X, 0), NW-1);
                        const bool vx = (X >= 0) & (X < NW);
                        const float wgt = (vx & vy) ? wxv[i]*wyv[j] : 0.f;
                        uint4 u = *(const uint4*)(vmb + (size_t)(Yc*NW + Xc)*ND);
                        const floatx2 w2 = {wgt, wgt};
                        acc[0] += w2 * fp8x2_to_f32<false>(u.x);
                        acc[1] += w2 * fp8x2_to_f32<true >(u.x);
                        acc[2] += w2 * fp8x2_to_f32<false>(u.y);
                        acc[3] += w2 * fp8x2_to_f32<true >(u.y);
                        acc[4] += w2 * fp8x2_to_f32<false>(u.z);
                        acc[5] += w2 * fp8x2_to_f32<true >(u.z);
                        acc[6] += w2 * fp8x2_to_f32<false>(u.w);
                        acc[7] += w2 * fp8x2_to_f32<true >(u.w);
                    }
                }
                const float s9 = 1.f/9.f;
                unsigned pk[8];
                #pragma unroll
                for (int k = 0; k < 8; ++k)
                    pk[k] = pk_bf16(acc[k].x*s9, acc[k].y*s9);
                *(uint4*)&feat[pt*136 + c8*16]     = make_uint4(pk[0],pk[1],pk[2],pk[3]);
                *(uint4*)&feat[pt*136 + c8*16 + 8] = make_uint4(pk[4],pk[5],pk[6],pk[7]);
            }
        }
        __syncthreads();

        // ---- Phase B: layer 1 (+layer-2 partials). thread=(point, 16-wide e-block) ----
        {
            const int pt = t & 63;
            const int eb = t >> 6;
            if (pt < np) {
                const int e0 = __builtin_amdgcn_readfirstlane(eb * 16);
                floatx2 acc[8];
                #pragma unroll
                for (int k = 0; k < 8; ++k) acc[k] = *(const floatx2*)&b1[e0 + 2*k];
                #pragma unroll 2
                for (int d = 0; d < ND; d += 8) {
                    ushort8 u = *(const ushort8*)&feat[pt*136 + d];
                    #pragma unroll
                    for (int jj = 0; jj < 8; ++jj) {
                        const float fv = bf2f(u[jj]);
                        const floatx2 f2 = {fv, fv};
                        const float* wrow = W1T + (size_t)(d + jj)*ND + e0;
                        #pragma unroll
                        for (int k = 0; k < 8; ++k)
                            acc[k] += f2 * (*(const floatx2*)&wrow[2*k]);
                    }
                }
                float s0 = 0.f, s1 = 0.f;
                const float* w20 = W2 + e0;
                const float* w21 = W2 + ND + e0;
                #pragma unroll
                for (int k = 0; k < 8; ++k) {
                    float h0 = fmaxf(acc[k].x, 0.f);
                    float h1 = fmaxf(acc[k].y, 0.f);
                    s0 = fmaf(h0, w20[2*k], fmaf(h1, w20[2*k+1], s0));
                    s1 = fmaf(h0, w21[2*k], fmaf(h1, w21[2*k+1], s1));
                }
                part[pt][eb*2 + 0] = s0;
                part[pt][eb*2 + 1] = s1;
            }
        }
        __syncthreads();

        // ---- Phase C: reduce 8 e-blocks, tanh, scatter-write ----
        if (t < np) {
            const int g = gidx[t];
            float s0 = 0.f, s1 = 0.f;
            #pragma unroll
            for (int k = 0; k < 8; ++k) { s0 += part[t][2*k]; s1 += part[t][2*k+1]; }
            const float cx = coords[(size_t)g*2 + 0];
            const float cy = coords[(size_t)g*2 + 1];
            const float MD = 0.5f / 512.0f;
            float2 o = make_float2(cx + tanhf(s0 + b2[0]) * MD,
                                   cy + tanhf(s1 + b2[1]) * MD);
            *(float2*)&out[(size_t)g*2] = o;
        }
        __syncthreads();
    }
}

extern "C" void kernel_launch(void* const* d_in, const int* in_sizes, int n_in,
                              void* d_out, int out_size, void* d_ws, size_t ws_size,
                              hipStream_t stream)
{
    const float* fmap   = (const float*)d_in[0];
    const float* coords = (const float*)d_in[1];
    const float* Wp     = (const float*)d_in[2];
    const float* W1     = (const float*)d_in[3];
    const float* b1     = (const float*)d_in[4];
    const float* W2     = (const float*)d_in[5];
    const float* b2     = (const float*)d_in[6];
    float* out = (float*)d_out;

    // ws layout
    unsigned char* vm = (unsigned char*)d_ws;                         // 8 MB fp8
    char* base = (char*)d_ws + (size_t)NB*NHW*ND;
    float* W1T   = (float*)base;                                      // 64 KB
    int* counts  = (int*)(base + 65536);                              // 4 KB
    int* cursor  = (int*)(base + 65536 + 4096);                       // 4 KB
    int* starts  = (int*)(base + 65536 + 8192);                       // 4 KB
    int* order   = (int*)(base + 65536 + 12288);                      // 256 KB

    prep_kernel   <<<dim3(1),   1024, 0, stream>>>(W1, W1T, counts, cursor);
    hist_kernel   <<<dim3(64),  1024, 0, stream>>>(coords, counts);
    scan_kernel   <<<dim3(1),   1024, 0, stream>>>(counts, starts);
    scatter_kernel<<<dim3(64),  1024, 0, stream>>>(coords, starts, cursor, order);
    proj_kernel   <<<dim3(512),  512, 0, stream>>>(fmap, Wp, vm);
    gather_mlp    <<<dim3(NBKT), 512, 0, stream>>>(vm, coords, counts, starts, order,
                                                   W1T, b1, W2, b2, out);
}

// Round 7
// 152.042 us; speedup vs baseline: 1.4287x; 1.4287x over previous
//
#include <hip/hip_runtime.h>
#include <cstddef>

#define NB 4
#define NC 256
#define ND 128
#define NH 128
#define NW 128
#define NHW (NH*NW)
#define NT 16384
#define NBKT 1024   // 4 batches x 16x16 tiles of 8x8 px
#define CAP 192     // per-bucket capacity (mean 64, P(>192) ~ e^-64: never)
#define FS 136      // feat row stride in ushorts

typedef short   short8  __attribute__((ext_vector_type(8)));
typedef unsigned short ushort8 __attribute__((ext_vector_type(8)));
typedef float   floatx4 __attribute__((ext_vector_type(4)));
typedef float   floatx2 __attribute__((ext_vector_type(2)));

__device__ __forceinline__ unsigned pk_bf16(float a, float b) {
    unsigned ua = __float_as_uint(a);
    unsigned ub = __float_as_uint(b);
    ua += 0x7fffu + ((ua >> 16) & 1u);
    ub += 0x7fffu + ((ub >> 16) & 1u);
    return (ua >> 16) | (ub & 0xffff0000u);
}

// ---- fp8 e4m3 (OCP) HW cvt ----
__device__ __forceinline__ unsigned fp8x4_from_f32(float v0, float v1, float v2, float v3) {
    int r = 0;
    r = __builtin_amdgcn_cvt_pk_fp8_f32(v0, v1, r, false);
    r = __builtin_amdgcn_cvt_pk_fp8_f32(v2, v3, r, true);
    return (unsigned)r;
}
template <bool HI>
__device__ __forceinline__ floatx2 fp8x2_to_f32(unsigned w) {
    return __builtin_amdgcn_cvt_pk_f32_fp8((int)w, HI);
}

__device__ __forceinline__ int bucket_of(float cx, float cy, int b) {
    int x0 = (int)floorf(cx * (float)(NW - 1));
    int y0 = (int)floorf(cy * (float)(NH - 1));
    x0 = min(max(x0, 0), NW - 1);
    y0 = min(max(y0, 0), NH - 1);
    return b * 256 + (y0 >> 3) * 16 + (x0 >> 3);
}

// ---- single-pass bucket scatter (capacity-strided: no hist/scan) + W1->bf16 prep ----
__global__ __launch_bounds__(1024)
void fill_kernel(const float* __restrict__ coords, const float* __restrict__ W1,
                 int* __restrict__ counts, int* __restrict__ order,
                 unsigned short* __restrict__ W1bf)
{
    const int bi = blockIdx.x;
    if (bi >= 64) {   // 16 blocks: W1 (e,d) fp32 -> bf16 row-major (= MFMA A-operand)
        const int i = (bi - 64) * 1024 + threadIdx.x;
        unsigned u = __float_as_uint(W1[i]);
        u += 0x7fffu + ((u >> 16) & 1u);
        W1bf[i] = (unsigned short)(u >> 16);
        return;
    }
    const int g = bi * 1024 + threadIdx.x;   // [0, 65536)
    const float cx = coords[(size_t)g*2 + 0];
    const float cy = coords[(size_t)g*2 + 1];
    const int bkt = bucket_of(cx, cy, g >> 14);
    const int pos = atomicAdd(&counts[bkt], 1);
    if (pos < CAP) order[bkt*CAP + pos] = g;
}

// vm[b][p][d] = sum_c fmap[b][c][p]*Wp[d][c], fp8 e4m3 channel-last.
// Wp staged once to LDS as bf16 A-fragments; K-loop fully unrolled.
__global__ __launch_bounds__(512, 4)
void proj_kernel(const float* __restrict__ fmap, const float* __restrict__ Wp,
                 unsigned char* __restrict__ vm)
{
    const int bi = blockIdx.x;
    __shared__ unsigned short awp[8*8*64*8];   // 64 KB

    const int t    = threadIdx.x;
    const int lane = t & 63;
    const int w    = t >> 6;
    const int l15  = lane & 15;
    const int q    = lane >> 4;
    const int cq   = q * 8;

    {
        const int dt = w;
        const float* wr0 = Wp + (size_t)(dt*16 + l15)*NC + cq;
        #pragma unroll
        for (int ch = 0; ch < 8; ++ch) {
            float4 g0 = *(const float4*)(wr0 + ch*32);
            float4 g1 = *(const float4*)(wr0 + ch*32 + 4);
            uint4 pk = make_uint4(pk_bf16(g0.x,g0.y), pk_bf16(g0.z,g0.w),
                                  pk_bf16(g1.x,g1.y), pk_bf16(g1.z,g1.w));
            *(uint4*)&awp[((dt*8 + ch)*64 + lane)*8] = pk;
        }
    }
    __syncthreads();

    const int b    = (bi & 7) >> 1;
    const int slot = ((bi >> 3) << 1) | (bi & 1);
    const int p    = slot*128 + w*16 + l15;

    floatx4 acc[8];
    #pragma unroll
    for (int i = 0; i < 8; ++i) acc[i] = (floatx4)(0.f);

    const float* fbase = fmap + (size_t)b*NC*NHW + p;

    #pragma unroll
    for (int c0 = 0; c0 < 8; ++c0) {
        const float* bp = fbase + (size_t)(c0*32 + cq)*NHW;
        float f[8];
        #pragma unroll
        for (int j = 0; j < 8; ++j) f[j] = bp[(size_t)j*NHW];
        union { short8 v; unsigned u[4]; } bc;
        #pragma unroll
        for (int j = 0; j < 4; ++j) bc.u[j] = pk_bf16(f[2*j], f[2*j+1]);
        #pragma unroll
        for (int dt = 0; dt < 8; ++dt) {
            short8 afr = *(const short8*)&awp[((dt*8 + c0)*64 + lane)*8];
            acc[dt] = __builtin_amdgcn_mfma_f32_16x16x32_bf16(afr, bc.v, acc[dt], 0, 0, 0);
        }
    }
    unsigned char* vrow = vm + ((size_t)(b*NHW + p))*ND;
    #pragma unroll
    for (int dt = 0; dt < 8; ++dt) {
        floatx4 v = acc[dt];
        *(unsigned*)&vrow[dt*16 + q*4] = fp8x4_from_f32(v[0], v[1], v[2], v[3]);
    }
}

// Gather (spatially bucketed, L1-resident vm patch) + MFMA MLP.
// Block = bucket; chunks of 64 pts. Phase B: h = W1(128x128) @ feat^T(128x64)
// via 16 MFMA/wave (wave owns 2 e-tiles x 2 pt-tiles x 4 K-steps); layer 2
// folded into epilogue with shfl_xor reduce over q-quads.
__global__ __launch_bounds__(512, 4)
void gather_mlp(const unsigned char* __restrict__ vm, const float* __restrict__ coords,
                const int* __restrict__ counts, const int* __restrict__ order,
                const unsigned short* __restrict__ W1bf, const float* __restrict__ b1,
                const float* __restrict__ W2, const float* __restrict__ b2,
                float* __restrict__ out)
{
    __shared__ unsigned short feat[64 * FS];
    __shared__ float part[64][8];
    __shared__ float W2s[256];   // (e -> [W2[0][e], W2[1][e]])
    __shared__ float b1s[128];
    __shared__ int gidx[64];
    const int t   = threadIdx.x;
    const int bkt = blockIdx.x;
    const int n      = min(counts[bkt], CAP);
    const int chunks = (n + 63) >> 6;

    if (t < 128) {
        W2s[t*2]   = W2[t];
        W2s[t*2+1] = W2[ND + t];
        b1s[t]     = b1[t];
    }
    __syncthreads();

    for (int c = 0; c < chunks; ++c) {
        const int np = min(n - c*64, 64);

        // ---- Phase A: gather. 8 threads/pt, 16 fp8 channels each. ----
        {
            const int pt = t >> 3;
            const int c8 = t & 7;
            if (pt < np) {
                const int g = order[bkt*CAP + c*64 + pt];
                if (c8 == 0) gidx[pt] = g;
                const int b = g >> 14;
                const float cx = coords[(size_t)g*2 + 0];
                const float cy = coords[(size_t)g*2 + 1];
                const float ix = cx * (float)(NW - 1);
                const float iy = cy * (float)(NH - 1);
                const float x0f = floorf(ix), y0f = floorf(iy);
                const int x0 = (int)x0f, y0 = (int)y0f;
                const float wx1 = ix - x0f, wy1 = iy - y0f;
                const float wxv[4] = {1.f - wx1, 1.f, 1.f, wx1};
                const float wyv[4] = {1.f - wy1, 1.f, 1.f, wy1};
                floatx2 acc[8];
                #pragma unroll
                for (int k = 0; k < 8; ++k) acc[k] = (floatx2)(0.f);
                const unsigned char* vmb = vm + (size_t)b*NHW*ND + c8*16;
                #pragma unroll
                for (int j = 0; j < 4; ++j) {
                    const int Y  = y0 - 1 + j;
                    const int Yc = min(max(Y, 0), NH-1);
                    const bool vy = (Y >= 0) & (Y < NH);
                    #pragma unroll
                    for (int i = 0; i < 4; ++i) {
                        const int X  = x0 - 1 + i;
                        const int Xc = min(max(X, 0), NW-1);
                        const bool vx = (X >= 0) & (X < NW);
                        const float wgt = (vx & vy) ? wxv[i]*wyv[j] : 0.f;
                        uint4 u = *(const uint4*)(vmb + (size_t)(Yc*NW + Xc)*ND);
                        const floatx2 w2 = {wgt, wgt};
                        acc[0] += w2 * fp8x2_to_f32<false>(u.x);
                        acc[1] += w2 * fp8x2_to_f32<true >(u.x);
                        acc[2] += w2 * fp8x2_to_f32<false>(u.y);
                        acc[3] += w2 * fp8x2_to_f32<true >(u.y);
                        acc[4] += w2 * fp8x2_to_f32<false>(u.z);
                        acc[5] += w2 * fp8x2_to_f32<true >(u.z);
                        acc[6] += w2 * fp8x2_to_f32<false>(u.w);
                        acc[7] += w2 * fp8x2_to_f32<true >(u.w);
                    }
                }
                const float s9 = 1.f/9.f;
                unsigned pk[8];
                #pragma unroll
                for (int k = 0; k < 8; ++k)
                    pk[k] = pk_bf16(acc[k].x*s9, acc[k].y*s9);
                *(uint4*)&feat[pt*FS + c8*16]     = make_uint4(pk[0],pk[1],pk[2],pk[3]);
                *(uint4*)&feat[pt*FS + c8*16 + 8] = make_uint4(pk[4],pk[5],pk[6],pk[7]);
            }
        }
        __syncthreads();

        // ---- Phase B: MFMA MLP. wave w: e-pair mp=w&3, pt-pair npr=w>>2. ----
        {
            const int lane = t & 63;
            const int w    = t >> 6;
            const int l15  = lane & 15;
            const int q    = lane >> 4;
            const int mp   = w & 3;
            const int npr  = w >> 2;

            floatx4 C[2][2];
            #pragma unroll
            for (int mi = 0; mi < 2; ++mi)
                #pragma unroll
                for (int ni = 0; ni < 2; ++ni) C[mi][ni] = (floatx4)(0.f);

            #pragma unroll
            for (int kk = 0; kk < 4; ++kk) {
                short8 a0 = *(const short8*)&W1bf[((mp*2+0)*16 + l15)*ND + kk*32 + q*8];
                short8 a1 = *(const short8*)&W1bf[((mp*2+1)*16 + l15)*ND + kk*32 + q*8];
                short8 f0 = *(const short8*)&feat[((npr*2+0)*16 + l15)*FS + kk*32 + q*8];
                short8 f1 = *(const short8*)&feat[((npr*2+1)*16 + l15)*FS + kk*32 + q*8];
                C[0][0] = __builtin_amdgcn_mfma_f32_16x16x32_bf16(a0, f0, C[0][0], 0, 0, 0);
                C[0][1] = __builtin_amdgcn_mfma_f32_16x16x32_bf16(a0, f1, C[0][1], 0, 0, 0);
                C[1][0] = __builtin_amdgcn_mfma_f32_16x16x32_bf16(a1, f0, C[1][0], 0, 0, 0);
                C[1][1] = __builtin_amdgcn_mfma_f32_16x16x32_bf16(a1, f1, C[1][1], 0, 0, 0);
            }
            // epilogue: e = (mp*2+mi)*16 + q*4 + reg ; pt = (npr*2+ni)*16 + l15
            #pragma unroll
            for (int ni = 0; ni < 2; ++ni) {
                float s0 = 0.f, s1 = 0.f;
                #pragma unroll
                for (int mi = 0; mi < 2; ++mi) {
                    const int e0 = (mp*2 + mi)*16 + q*4;
                    float4 bq = *(const float4*)&b1s[e0];
                    floatx4 h4 = C[mi][ni];
                    #pragma unroll
                    for (int r = 0; r < 4; ++r) {
                        float hv = fmaxf(h4[r] + (&bq.x)[r], 0.f);
                        float2 wv = *(const float2*)&W2s[(e0 + r)*2];
                        s0 = fmaf(hv, wv.x, s0);
                        s1 = fmaf(hv, wv.y, s1);
                    }
                }
                s0 += __shfl_xor(s0, 16); s0 += __shfl_xor(s0, 32);
                s1 += __shfl_xor(s1, 16); s1 += __shfl_xor(s1, 32);
                if (q == 0) {
                    const int pt = (npr*2 + ni)*16 + l15;
                    part[pt][mp*2 + 0] = s0;
                    part[pt][mp*2 + 1] = s1;
                }
            }
        }
        __syncthreads();

        // ---- Phase C: reduce 4 e-pairs, tanh, scatter-write ----
        if (t < np) {
            const int g = gidx[t];
            float s0 = part[t][0] + part[t][2] + part[t][4] + part[t][6];
            float s1 = part[t][1] + part[t][3] + part[t][5] + part[t][7];
            const float cx = coords[(size_t)g*2 + 0];
            const float cy = coords[(size_t)g*2 + 1];
            const float MD = 0.5f / 512.0f;
            float2 o = make_float2(cx + tanhf(s0 + b2[0]) * MD,
                                   cy + tanhf(s1 + b2[1]) * MD);
            *(float2*)&out[(size_t)g*2] = o;
        }
        __syncthreads();
    }
}

extern "C" void kernel_launch(void* const* d_in, const int* in_sizes, int n_in,
                              void* d_out, int out_size, void* d_ws, size_t ws_size,
                              hipStream_t stream)
{
    const float* fmap   = (const float*)d_in[0];
    const float* coords = (const float*)d_in[1];
    const float* Wp     = (const float*)d_in[2];
    const float* W1     = (const float*)d_in[3];
    const float* b1     = (const float*)d_in[4];
    const float* W2     = (const float*)d_in[5];
    const float* b2     = (const float*)d_in[6];
    float* out = (float*)d_out;

    // ws layout
    unsigned char* vm = (unsigned char*)d_ws;                         // 8 MB fp8
    char* base = (char*)d_ws + (size_t)NB*NHW*ND;
    unsigned short* W1bf = (unsigned short*)base;                     // 32 KB bf16
    int* counts = (int*)(base + 32768);                               // 4 KB
    int* order  = (int*)(base + 32768 + 4096);                        // 768 KB

    hipMemsetAsync(counts, 0, NBKT*sizeof(int), stream);
    fill_kernel<<<dim3(64 + 16), 1024, 0, stream>>>(coords, W1, counts, order, W1bf);
    proj_kernel<<<dim3(512),      512, 0, stream>>>(fmap, Wp, vm);
    gather_mlp <<<dim3(NBKT),     512, 0, stream>>>(vm, coords, counts, order,
                                                    W1bf, b1, W2, b2, out);
}